// Round 12
// baseline (603.861 us; speedup 1.0000x reference)
//
#include <hip/hip_runtime.h>

typedef float vf4 __attribute__((ext_vector_type(4)));
typedef int vi4 __attribute__((ext_vector_type(4)));
typedef short short8 __attribute__((ext_vector_type(8)));
typedef unsigned short ushort8 __attribute__((ext_vector_type(8)));
typedef float f32x16 __attribute__((ext_vector_type(16)));

#define LL 1024
#define DD 64
#define OO 128
#define BBATCH 4096
#define NS 511          // scan sites per sweep
#define SITE_F 8192     // elements per site tensor (64*2*64)

// ---- async global->LDS ----
__device__ __forceinline__ void gld_lds16(const float* g, float* l) {
  __builtin_amdgcn_global_load_lds(
      (const __attribute__((address_space(1))) unsigned int*)g,
      (__attribute__((address_space(3))) unsigned int*)l, 16, 0, 0);
}

__device__ __forceinline__ void stage32k_256(float* lds, const float* g, int tid) {
#pragma unroll
  for (int q = 0; q < 8; q++) {
    const int off = (q * 256 + tid) * 4;
    gld_lds16(g + off, lds + off);
  }
}

// ---- one-shot: build bf16 32x32x16-frag-major N = A - I for both sweeps ----
// layout: W[site][sm][lane][j] bf16, sm = s*2+mt (s=K-step 0..7, mt=M-tile 0..1)
// element = N[k2][n], k2 = 16s + 8*(lane>>5) + j, n = 32*mt + (lane&31)
// right buffer is site-reversed so the sweep always walks ascending.
// (verbatim from R3..R6 — numerics proven, absmax 2.441e-3)
__global__ __launch_bounds__(256) void prep(const float* __restrict__ lsrc,
                                            const float* __restrict__ rsrc,
                                            unsigned short* __restrict__ Wl,
                                            unsigned short* __restrict__ Wr) {
  __shared__ float S[SITE_F];
  const int site = blockIdx.x;
  const int dir = blockIdx.y;
  const int tid = threadIdx.x;
  const float* src = (dir ? rsrc : lsrc) + (size_t)site * SITE_F;
  unsigned short* dst = dir ? (Wr + (size_t)(NS - 1 - site) * SITE_F)
                            : (Wl + (size_t)site * SITE_F);
#pragma unroll
  for (int m = 0; m < 8; m++)
    *(vf4*)&S[(m * 256 + tid) * 4] = *(const vf4*)&src[(m * 256 + tid) * 4];
  __syncthreads();
#pragma unroll
  for (int q = 0; q < 4; q++) {
    const int slot = q * 256 + tid;           // 0..1023 = sm*64 + lane
    const int lane = slot & 63, sm = slot >> 6;
    const int s = sm >> 1, mt = sm & 1;
    const int hi = lane >> 5, ln = lane & 31;
    const int n = 32 * mt + ln;
    ushort8 t;
#pragma unroll
    for (int j = 0; j < 8; j++) {
      const int k2 = 16 * s + 8 * hi + j;
      float v;
      if (dir == 0) {
        v = S[k2 * 64 + n] - ((n == (k2 >> 1)) ? 1.f : 0.f);
      } else {
        const int r = k2 >> 1, p = k2 & 1;
        v = S[n * 128 + p * 64 + r] - ((n == r) ? 1.f : 0.f);
      }
      const unsigned uu = __builtin_bit_cast(unsigned, v);
      t[j] = (unsigned short)((uu + 0x7FFFu + ((uu >> 16) & 1u)) >> 16);  // RNE
    }
    *(ushort8*)&dst[(size_t)slot * 8] = t;
  }
}

// ---- stage one 16KB site into ring slot (16 gld_lds16, counted by vmcnt) ----
#define STAGE(SLOT2, SITE)                                                     \
  {                                                                            \
    const float* Ws_ = Wf + (size_t)(SITE) * 4096;                             \
    float* d_ = &ring[SLOT2][0];                                               \
    _Pragma("unroll")                                                          \
    for (int q = 0; q < 16; q++)                                               \
      gld_lds16(Ws_ + q * 256 + lane * 4, d_ + q * 256 + lane * 4);            \
  }

// ---- per-site body (ring-4, LDS-only async, compiler ds_read) ----
// SLOT: ring slot of site I (compile-time). CS/SN: cos/sin(site I); if CSC,
// recomputed with site I+2's (from XS = x(I+2)); XS then reloaded with x(I+4)
// when PFW. VC: counted wait so slot SLOT's 16 stages are retired.
#define BODY(I, SLOT, CS, SN, XS, PFW, CSC, VC)                                \
  {                                                                            \
    asm volatile("s_waitcnt vmcnt(" #VC ")" ::: "memory");                     \
    __builtin_amdgcn_sched_barrier(0);                                         \
    vf4 FC[16];                                                                \
    _Pragma("unroll")                                                          \
    for (int q = 0; q < 16; q++)                                               \
      FC[q] = *(const vf4*)&ring[SLOT][q * 256 + lane * 4];                    \
    short8 e2[8];                                                              \
    _Pragma("unroll")                                                          \
    for (int s = 0; s < 8; s++) {                                              \
      int pk[4];                                                               \
      _Pragma("unroll")                                                        \
      for (int t = 0; t < 4; t++) {                                            \
        const float uv = u[s >> 2][(s & 3) * 4 + t];                           \
        const float f0 = uv * CS, f1 = uv * SN;                                \
        int p;                                                                 \
        asm("v_cvt_pk_bf16_f32 %0, %1, %2" : "=v"(p) : "v"(f0), "v"(f1));      \
        pk[t] = p;                                                             \
      }                                                                        \
      e2[s] = __builtin_bit_cast(short8, (vi4){pk[0], pk[1], pk[2], pk[3]});   \
    }                                                                          \
    const float keff = CS + SN;                                                \
    f32x16 a0a, a1a;                                                           \
    f32x16 a0b = {}, a1b = {};                                                 \
    _Pragma("unroll")                                                          \
    for (int r = 0; r < 16; r++) {                                             \
      a0a[r] = keff * u[0][r];                                                 \
      a1a[r] = keff * u[1][r];                                                 \
    }                                                                          \
    _Pragma("unroll")                                                          \
    for (int s = 0; s < 4; s++) {                                              \
      a0a = __builtin_amdgcn_mfma_f32_32x32x16_bf16(                           \
          __builtin_bit_cast(short8, FC[2 * s]), e2[s], a0a, 0, 0, 0);         \
      a1a = __builtin_amdgcn_mfma_f32_32x32x16_bf16(                           \
          __builtin_bit_cast(short8, FC[2 * s + 1]), e2[s], a1a, 0, 0, 0);     \
    }                                                                          \
    _Pragma("unroll")                                                          \
    for (int s = 4; s < 8; s++) {                                              \
      a0b = __builtin_amdgcn_mfma_f32_32x32x16_bf16(                           \
          __builtin_bit_cast(short8, FC[2 * s]), e2[s], a0b, 0, 0, 0);         \
      a1b = __builtin_amdgcn_mfma_f32_32x32x16_bf16(                           \
          __builtin_bit_cast(short8, FC[2 * s + 1]), e2[s], a1b, 0, 0, 0);     \
    }                                                                          \
    const float xt_ = XS; /* x(I+2), read BEFORE any reload */                 \
    if (PFW) {                                                                 \
      STAGE((((SLOT) + 3) & 3), (I) + 3)                                       \
      XS = xrow[dir ? (1018 - (I)) : (5 + (I))]; /* x(I+4), compiler load */   \
      __builtin_amdgcn_sched_barrier(0);                                       \
    }                                                                          \
    if (CSC) {                                                                 \
      const float qrev = 0.25f * xt_; /* cos(pi/2 x) = cos(2pi*(x/4)) */       \
      float c_, s_;                                                            \
      asm("v_cos_f32 %0, %1" : "=v"(c_) : "v"(qrev));                          \
      asm("v_sin_f32 %0, %1" : "=v"(s_) : "v"(qrev));                          \
      CS = c_;                                                                 \
      SN = s_;                                                                 \
    }                                                                          \
    u[0] = a0a + a0b;                                                          \
    u[1] = a1a + a1b;                                                          \
    if (((I) & 7) == 7) { /* exact pow2 rescale, keeps fp32 in range */        \
      float nss = 0.f;                                                         \
      _Pragma("unroll")                                                        \
      for (int r = 0; r < 16; r++)                                             \
        nss += u[0][r] * u[0][r] + u[1][r] * u[1][r];                          \
      nss += __shfl_xor(nss, 32);                                              \
      const int eb = (__float_as_int(nss) >> 23) & 0xFF;                       \
      const float alpha = __int_as_float((127 - ((eb - 127) >> 1)) << 23);     \
      _Pragma("unroll")                                                        \
      for (int r = 0; r < 16; r++) { u[0][r] *= alpha; u[1][r] *= alpha; }     \
    }                                                                          \
  }

// ---- sweep: 1 wave = 32 chains; LDS ring-4; counted vmcnt; no barriers ----
// 256 blocks (1/CU). XCD swizzle: XCDs 0-3 -> dir 0, XCDs 4-7 -> dir 1.
__global__ __launch_bounds__(64, 1) void sweep(const float* __restrict__ x,
                                               const float* __restrict__ left0,
                                               const float* __restrict__ right_last,
                                               const unsigned short* __restrict__ Wl,
                                               const unsigned short* __restrict__ Wr,
                                               float* __restrict__ envL,
                                               float* __restrict__ envR) {
  __shared__ float ring[4][4096];        // 4 x 16KB site-frag ring
  const int bid = blockIdx.x;
  const int xcd = bid & 7;
  const int dir = xcd >> 2;
  const int pr = (xcd & 3) * 32 + (bid >> 3);   // 0..127
  const int lane = threadIdx.x;
  const int hi = lane >> 5, ln = lane & 31;
  const int b = pr * 32 + ln;
  const float* xrow = x + (size_t)b * LL;

  const float* Wf = (const float*)(dir ? Wr : Wl);

  // init env from boundary tensor (fp32, exact normalize; compiler loads)
  f32x16 u[2];
  {
    const float x0 = xrow[dir ? (LL - 1) : 0];
    const float qrev = 0.25f * x0;
    float cs, sn;
    asm("v_cos_f32 %0, %1" : "=v"(cs) : "v"(qrev));
    asm("v_sin_f32 %0, %1" : "=v"(sn) : "v"(qrev));
#pragma unroll
    for (int mt = 0; mt < 2; mt++)
#pragma unroll
      for (int r = 0; r < 16; r++) {
        const int n = 32 * mt + 8 * (r >> 2) + 4 * hi + (r & 3);
        const float w0 = dir ? right_last[n * 2] : left0[n];
        const float w1 = dir ? right_last[n * 2 + 1] : left0[64 + n];
        u[mt][r] = cs * w0 + sn * w1;
      }
    float ss = 0.f;
#pragma unroll
    for (int mt = 0; mt < 2; mt++)
#pragma unroll
      for (int r = 0; r < 16; r++) ss += u[mt][r] * u[mt][r];
    ss += __shfl_xor(ss, 32);
    const float a0 = 1.f / (sqrtf(ss) + 1e-8f);
#pragma unroll
    for (int mt = 0; mt < 2; mt++)
#pragma unroll
      for (int r = 0; r < 16; r++) u[mt][r] *= a0;
  }

  // cs/sn(site 0, site 1) + x ring regs (compiler loads, precise waits)
  float csE, snE, csO, snO;
  {
    const float q0 = 0.25f * xrow[dir ? 1022 : 1];   // site 0
    asm("v_cos_f32 %0, %1" : "=v"(csE) : "v"(q0));
    asm("v_sin_f32 %0, %1" : "=v"(snE) : "v"(q0));
    const float q1 = 0.25f * xrow[dir ? 1021 : 2];   // site 1
    asm("v_cos_f32 %0, %1" : "=v"(csO) : "v"(q1));
    asm("v_sin_f32 %0, %1" : "=v"(snO) : "v"(q1));
  }
  float xvA = xrow[dir ? 1020 : 3];   // x(site 2)
  float xvB = xrow[dir ? 1019 : 4];   // x(site 3)

  // ---- prologue: stage sites 0..2 into slots 0..2 (48 counted ops) ----
  STAGE(0, 0)
  STAGE(1, 1)
  STAGE(2, 2)
  __builtin_amdgcn_sched_barrier(0);

  // ---- main loop: sites 0..507 (ring-4, lead-3), tail 508..510 ----
  for (int i = 0; i < 508; i += 4) {
    BODY(i, 0, csE, snE, xvA, 1, 1, 32)
    BODY(i + 1, 1, csO, snO, xvB, 1, 1, 32)
    BODY(i + 2, 2, csE, snE, xvA, 1, 1, 32)
    BODY(i + 3, 3, csO, snO, xvB, 1, 1, 32)
  }
  BODY(508, 0, csE, snE, xvA, 0, 1, 32)   // computes cs/sn(510) from x(510)
  BODY(509, 1, csO, snO, xvB, 0, 0, 16)
  BODY(510, 2, csE, snE, xvA, 0, 0, 0)

  // final exact normalize + store
  float nss = 0.f;
#pragma unroll
  for (int mt = 0; mt < 2; mt++)
#pragma unroll
    for (int r = 0; r < 16; r++) nss += u[mt][r] * u[mt][r];
  nss += __shfl_xor(nss, 32);
  const float alpha = 1.f / (sqrtf(nss) + 1e-8f);

  float* eo = (dir ? envR : envL) + (size_t)b * 64;
#pragma unroll
  for (int mt = 0; mt < 2; mt++)
#pragma unroll
    for (int g = 0; g < 4; g++) {
      vf4 v;
#pragma unroll
      for (int q = 0; q < 4; q++) v[q] = u[mt][g * 4 + q] * alpha;
      *(vf4*)&eo[32 * mt + 8 * g + 4 * hi] = v;
    }
}

// ---- center contraction (fp32) ----
__global__ __launch_bounds__(256) void centerk(const float* __restrict__ envL,
                                               const float* __restrict__ envR,
                                               const float* __restrict__ center,
                                               float* __restrict__ Pp) {
  __shared__ float Cs[2][SITE_F];
  __shared__ float LT[64 * 36];
  __shared__ float RT[64 * 36];
  const int bbase = blockIdx.x * 32;
  const int half = blockIdx.y;
  const int tid = threadIdx.x;
  const int och = tid & 31, bch = tid >> 5;
  const int o0 = och * 4, b0 = bch * 4;
#pragma unroll
  for (int m = 0; m < 8; m++) {
    const int idx = m * 256 + tid;
    const int b = idx >> 6, l = idx & 63;
    LT[l * 36 + b] = envL[(bbase + b) * 64 + l];
    RT[l * 36 + b] = envR[(bbase + b) * 64 + l];
  }
  stage32k_256(Cs[0], center + (half * 32) * SITE_F, tid);
  float acc[4][4] = {};
  for (int lh = 0; lh < 32; lh++) {
    __syncthreads();
    const int buf = lh & 1;
    if (lh + 1 < 32) stage32k_256(Cs[buf ^ 1], center + (half * 32 + lh + 1) * SITE_F, tid);
    const vf4 lv = *(const vf4*)&LT[(half * 32 + lh) * 36 + b0];
    const float* C = Cs[buf];
#pragma unroll
    for (int r = 0; r < 64; r++) {
      const vf4 rv = *(const vf4*)&RT[r * 36 + b0];
      const vf4 cv = *(const vf4*)&C[r * 128 + o0];
#pragma unroll
      for (int i2 = 0; i2 < 4; i2++) {
        const float w = lv[i2] * rv[i2];
        acc[i2][0] += w * cv[0];
        acc[i2][1] += w * cv[1];
        acc[i2][2] += w * cv[2];
        acc[i2][3] += w * cv[3];
      }
    }
  }
#pragma unroll
  for (int i2 = 0; i2 < 4; i2++) {
    vf4 v; v[0] = acc[i2][0]; v[1] = acc[i2][1]; v[2] = acc[i2][2]; v[3] = acc[i2][3];
    *(vf4*)&Pp[(size_t)half * BBATCH * 128 + (size_t)(bbase + b0 + i2) * 128 + o0] = v;
  }
}

// ---- combine halves + row-normalize ----
__global__ __launch_bounds__(256) void combinek(const float* __restrict__ P,
                                                float* __restrict__ out) {
  const float* P0 = P;
  const float* P1 = P + (size_t)BBATCH * 128;
  const int row = blockIdx.x * 8 + (threadIdx.x >> 5);
  const int o0 = (threadIdx.x & 31) * 4;
  vf4 v = *(const vf4*)&P0[(size_t)row * 128 + o0];
  const vf4 v1 = *(const vf4*)&P1[(size_t)row * 128 + o0];
  v += v1;
  float ss = v[0] * v[0] + v[1] * v[1] + v[2] * v[2] + v[3] * v[3];
#pragma unroll
  for (int m = 1; m < 32; m <<= 1) ss += __shfl_xor(ss, m);
  const float inv = 1.f / fmaxf(sqrtf(ss), 1e-12f);
  v *= inv;
  *(vf4*)&out[(size_t)row * 128 + o0] = v;
}

extern "C" void kernel_launch(void* const* d_in, const int* in_sizes, int n_in,
                              void* d_out, int out_size, void* d_ws, size_t ws_size,
                              hipStream_t stream) {
  const float* x = (const float*)d_in[0];
  const float* left0 = (const float*)d_in[1];
  const float* left_rest = (const float*)d_in[2];
  const float* center = (const float*)d_in[3];
  const float* right_rest = (const float*)d_in[4];
  const float* right_last = (const float*)d_in[5];
  float* out = (float*)d_out;

  char* wsb = (char*)d_ws;
  unsigned short* Wl = (unsigned short*)wsb;                       // 8.37 MB
  unsigned short* Wr = Wl + (size_t)NS * SITE_F;                   // 8.37 MB
  float* envL = (float*)(Wr + (size_t)NS * SITE_F);                // 1 MB
  float* envR = envL + (size_t)BBATCH * 64;                        // 1 MB
  float* Pp = envR + (size_t)BBATCH * 64;                          // 4.2 MB

  hipLaunchKernelGGL(prep, dim3(NS, 2), dim3(256), 0, stream,
                     left_rest, right_rest, Wl, Wr);
  hipLaunchKernelGGL(sweep, dim3(256), dim3(64), 0, stream,
                     x, left0, right_last, Wl, Wr, envL, envR);
  hipLaunchKernelGGL(centerk, dim3(BBATCH / 32, 2), dim3(256), 0, stream,
                     envL, envR, center, Pp);
  hipLaunchKernelGGL(combinek, dim3(BBATCH / 8), dim3(256), 0, stream, Pp, out);
}

// Round 13
// 508.295 us; speedup vs baseline: 1.1880x; 1.1880x over previous
//
#include <hip/hip_runtime.h>

typedef float vf4 __attribute__((ext_vector_type(4)));
typedef int vi4 __attribute__((ext_vector_type(4)));
typedef short short8 __attribute__((ext_vector_type(8)));
typedef unsigned short ushort8 __attribute__((ext_vector_type(8)));

#define LL 1024
#define DD 64
#define OO 128
#define BBATCH 4096
#define NS 511          // scan sites per sweep
#define SITE_F 8192     // elements per site tensor (64*2*64)

// ---- async global->LDS ----
__device__ __forceinline__ void gld_lds16(const float* g, float* l) {
  __builtin_amdgcn_global_load_lds(
      (const __attribute__((address_space(1))) unsigned int*)g,
      (__attribute__((address_space(3))) unsigned int*)l, 16, 0, 0);
}
__device__ __forceinline__ void gld_lds4(const float* g, float* l) {
  __builtin_amdgcn_global_load_lds(
      (const __attribute__((address_space(1))) unsigned int*)g,
      (__attribute__((address_space(3))) unsigned int*)l, 4, 0, 0);
}

__device__ __forceinline__ void stage32k_256(float* lds, const float* g, int tid) {
#pragma unroll
  for (int q = 0; q < 8; q++) {
    const int off = (q * 256 + tid) * 4;
    gld_lds16(g + off, lds + off);
  }
}

// ---- one-shot: build bf16 16x16x32-frag-major N = A - I for both sweeps ----
// layout: W[site][f][lane][j] bf16, f = mt*4+s (mt=M-tile 0..3, s=K-step 0..3)
// A elem: m = 16*mt + (lane&15); k = 32*s + 8*(lane>>4) + j  (k = 2*env_in + p)
// right buffer is site-reversed so the sweep always walks ascending.
// (verbatim from R7 — numerics proven, absmax 2.441e-3)
__global__ __launch_bounds__(256) void prep(const float* __restrict__ lsrc,
                                            const float* __restrict__ rsrc,
                                            unsigned short* __restrict__ Wl,
                                            unsigned short* __restrict__ Wr) {
  __shared__ float S[SITE_F];
  const int site = blockIdx.x;
  const int dir = blockIdx.y;
  const int tid = threadIdx.x;
  const float* src = (dir ? rsrc : lsrc) + (size_t)site * SITE_F;
  unsigned short* dst = dir ? (Wr + (size_t)(NS - 1 - site) * SITE_F)
                            : (Wl + (size_t)site * SITE_F);
#pragma unroll
  for (int m = 0; m < 8; m++)
    *(vf4*)&S[(m * 256 + tid) * 4] = *(const vf4*)&src[(m * 256 + tid) * 4];
  __syncthreads();
#pragma unroll
  for (int q = 0; q < 4; q++) {
    const int slot = q * 256 + tid;           // 0..1023 = f*64 + lane
    const int lane = slot & 63, f = slot >> 6;
    const int mt = f >> 2, s = f & 3;
    const int g = lane >> 4, c = lane & 15;
    const int m = 16 * mt + c;
    ushort8 t;
#pragma unroll
    for (int j = 0; j < 8; j++) {
      const int k = 32 * s + 8 * g + j;
      float v;
      if (dir == 0) {
        const int l = k >> 1, p = k & 1;
        v = S[l * 128 + p * 64 + m] - ((m == l) ? 1.f : 0.f);
      } else {
        const int r = k >> 1, p = k & 1;
        v = S[m * 128 + p * 64 + r] - ((m == r) ? 1.f : 0.f);
      }
      const unsigned uu = __builtin_bit_cast(unsigned, v);
      t[j] = (unsigned short)((uu + 0x7FFFu + ((uu >> 16) & 1u)) >> 16);  // RNE
    }
    *(ushort8*)&dst[(size_t)slot * 8] = t;
  }
}

// ---- stage one 16KB site into ring slot (16 counted gld_lds16) ----
#define STAGE(SLOT, SITE)                                                      \
  {                                                                            \
    const float* Ws_ = Wf + (size_t)(SITE) * 4096;                             \
    float* d_ = &ring[SLOT][0];                                                \
    _Pragma("unroll")                                                          \
    for (int q = 0; q < 16; q++)                                               \
      gld_lds16(Ws_ + q * 256 + lane * 4, d_ + q * 256 + lane * 4);            \
  }

// ---- stage x chunk C (64 sites x 16 samples, [t][s] layout, 16 ops) ----
#define STAGE_X(C)                                                             \
  {                                                                            \
    float* xd_ = &xls[(C) & 1][0];                                             \
    _Pragma("unroll")                                                          \
    for (int q = 0; q < 16; q++) {                                             \
      const int tl_ = q * 4 + g;                                               \
      const int st_ = 64 * (C) + tl_;                                          \
      const int ti_ = dir ? (1022 - st_) : (1 + st_);                          \
      gld_lds4(xrow + ti_, xd_ + q * 64 + lane);                               \
    }                                                                          \
  }

// ---- per-site body: ring-4 LDS, counted vmcnt, zero compiler VMEM ----
// Invariant: at this wait, site I's 16 stages have >=32 younger vmem ops,
// so vmcnt(32) guarantees they are retired (in-order retire).
#define BODY(I, VCS)                                                           \
  {                                                                            \
    asm volatile("s_waitcnt vmcnt(" VCS ")" ::: "memory");                     \
    __builtin_amdgcn_sched_barrier(0);                                         \
    const float* rb = &ring[(I) & 3][0];                                       \
    vf4 FC[16];                                                                \
    _Pragma("unroll")                                                          \
    for (int q = 0; q < 16; q++)                                               \
      FC[q] = *(const vf4*)&rb[q * 256 + lane * 4];                            \
    short8 e2[4];                                                              \
    _Pragma("unroll")                                                          \
    for (int s = 0; s < 4; s++) {                                              \
      int pk[4];                                                               \
      _Pragma("unroll")                                                        \
      for (int t = 0; t < 4; t++) {                                            \
        const float f0 = u[s][t] * CS, f1 = u[s][t] * SN;                      \
        int p;                                                                 \
        asm("v_cvt_pk_bf16_f32 %0, %1, %2" : "=v"(p) : "v"(f0), "v"(f1));      \
        pk[t] = p;                                                             \
      }                                                                        \
      e2[s] = __builtin_bit_cast(short8, (vi4){pk[0], pk[1], pk[2], pk[3]});   \
    }                                                                          \
    const float keff = CS + SN;                                                \
    vf4 acc[4];                                                                \
    _Pragma("unroll")                                                          \
    for (int mt = 0; mt < 4; mt++) {                                           \
      vf4 z;                                                                   \
      z[0] = keff * u[mt][0]; z[1] = keff * u[mt][1];                          \
      z[2] = keff * u[mt][2]; z[3] = keff * u[mt][3];                          \
      acc[mt] = z;                                                             \
    }                                                                          \
    _Pragma("unroll")                                                          \
    for (int mt = 0; mt < 4; mt++) {                                           \
      acc[mt] = __builtin_amdgcn_mfma_f32_16x16x32_bf16(                       \
          __builtin_bit_cast(short8, FC[mt * 4 + 0]), e2[0], acc[mt], 0, 0, 0);\
      acc[mt] = __builtin_amdgcn_mfma_f32_16x16x32_bf16(                       \
          __builtin_bit_cast(short8, FC[mt * 4 + 1]), e2[1], acc[mt], 0, 0, 0);\
      acc[mt] = __builtin_amdgcn_mfma_f32_16x16x32_bf16(                       \
          __builtin_bit_cast(short8, FC[mt * 4 + 2]), e2[2], acc[mt], 0, 0, 0);\
      acc[mt] = __builtin_amdgcn_mfma_f32_16x16x32_bf16(                       \
          __builtin_bit_cast(short8, FC[mt * 4 + 3]), e2[3], acc[mt], 0, 0, 0);\
    }                                                                          \
    if ((I) + 3 <= NS - 1) { STAGE(((I) + 3) & 3, (I) + 3) }                   \
    if (((I) & 63) == 48 && (I) <= 432) { STAGE_X(((I) >> 6) + 1) }            \
    __builtin_amdgcn_sched_barrier(0);                                         \
    if ((I) <= NS - 2) { /* cs/sn(site I+1) from LDS x (lgkm domain) */        \
      const int nI = (I) + 1;                                                  \
      const float xv = xls[(nI >> 6) & 1][(nI & 63) * 16 + c];                 \
      const float qrev = 0.25f * xv;                                           \
      float c_, s_;                                                            \
      asm("v_cos_f32 %0, %1" : "=v"(c_) : "v"(qrev));                          \
      asm("v_sin_f32 %0, %1" : "=v"(s_) : "v"(qrev));                          \
      CS = c_;                                                                 \
      SN = s_;                                                                 \
    }                                                                          \
    _Pragma("unroll")                                                          \
    for (int mt = 0; mt < 4; mt++) u[mt] = acc[mt];                            \
    if (((I) & 7) == 7) { /* exact pow2 rescale, keeps fp32 in range */        \
      float nss = 0.f;                                                         \
      _Pragma("unroll")                                                        \
      for (int mt = 0; mt < 4; mt++)                                           \
        _Pragma("unroll")                                                      \
        for (int r = 0; r < 4; r++) nss += u[mt][r] * u[mt][r];                \
      nss += __shfl_xor(nss, 16);                                              \
      nss += __shfl_xor(nss, 32);                                              \
      const int eb = (__float_as_int(nss) >> 23) & 0xFF;                       \
      const float alpha = __int_as_float((127 - ((eb - 127) >> 1)) << 23);     \
      _Pragma("unroll")                                                        \
      for (int mt = 0; mt < 4; mt++)                                           \
        _Pragma("unroll")                                                      \
        for (int r = 0; r < 4; r++) u[mt][r] *= alpha;                         \
    }                                                                          \
  }

// ---- sweep: 512 waves of 16 chains (2 blocks/CU); LDS ring-4 + x chunks ----
// XCD swizzle: XCDs 0-3 -> dir 0, XCDs 4-7 -> dir 1.
__global__ __launch_bounds__(64, 1) void sweep(const float* __restrict__ x,
                                               const float* __restrict__ left0,
                                               const float* __restrict__ right_last,
                                               const unsigned short* __restrict__ Wl,
                                               const unsigned short* __restrict__ Wr,
                                               float* __restrict__ envL,
                                               float* __restrict__ envR) {
  __shared__ float ring[4][4096];        // 64 KB site-frag ring
  __shared__ float xls[2][1024];         // 8 KB x chunks, [t&63][16]
  const int bid = blockIdx.x;
  const int xcd = bid & 7;
  const int dir = xcd >> 2;
  const int pr = (xcd & 3) * 64 + (bid >> 3);   // 0..255
  const int lane = threadIdx.x;
  const int g = lane >> 4, c = lane & 15;
  const int b = pr * 16 + c;
  const float* xrow = x + (size_t)b * LL;

  const float* Wf = (const float*)(dir ? Wr : Wl);

  // init env from boundary tensor (fp32, exact normalize; compiler loads
  // happen before the pinned region and retire during the first drain)
  vf4 u[4];
  {
    const float x0 = xrow[dir ? (LL - 1) : 0];
    const float qrev = 0.25f * x0;
    float cs, sn;
    asm("v_cos_f32 %0, %1" : "=v"(cs) : "v"(qrev));
    asm("v_sin_f32 %0, %1" : "=v"(sn) : "v"(qrev));
#pragma unroll
    for (int mt = 0; mt < 4; mt++)
#pragma unroll
      for (int r = 0; r < 4; r++) {
        const int n = 16 * mt + 4 * g + r;
        const float w0 = dir ? right_last[n * 2] : left0[n];
        const float w1 = dir ? right_last[n * 2 + 1] : left0[64 + n];
        u[mt][r] = cs * w0 + sn * w1;
      }
    float ss = 0.f;
#pragma unroll
    for (int mt = 0; mt < 4; mt++)
#pragma unroll
      for (int r = 0; r < 4; r++) ss += u[mt][r] * u[mt][r];
    ss += __shfl_xor(ss, 16);
    ss += __shfl_xor(ss, 32);
    const float a0 = 1.f / (sqrtf(ss) + 1e-8f);
#pragma unroll
    for (int mt = 0; mt < 4; mt++)
#pragma unroll
      for (int r = 0; r < 4; r++) u[mt][r] *= a0;
  }

  // ---- prologue: x chunk 0 + ring sites 0..2; drain to x; cs/sn(0) ----
  STAGE_X(0)
  STAGE(0, 0)
  STAGE(1, 1)
  STAGE(2, 2)
  asm volatile("s_waitcnt vmcnt(48)" ::: "memory");   // x chunk 0 retired
  __builtin_amdgcn_sched_barrier(0);

  float CS, SN;
  {
    const float xv = xls[0][c];   // site 0
    const float qrev = 0.25f * xv;
    asm("v_cos_f32 %0, %1" : "=v"(CS) : "v"(qrev));
    asm("v_sin_f32 %0, %1" : "=v"(SN) : "v"(qrev));
  }

  // ---- main loop: sites 0..507, tail 508..510 ----
  for (int i = 0; i < NS - 3; i++) {
    BODY(i, "32")
  }
  BODY(NS - 3, "32")
  BODY(NS - 2, "16")
  BODY(NS - 1, "0")

  // final exact normalize + store
  float nss = 0.f;
#pragma unroll
  for (int mt = 0; mt < 4; mt++)
#pragma unroll
    for (int r = 0; r < 4; r++) nss += u[mt][r] * u[mt][r];
  nss += __shfl_xor(nss, 16);
  nss += __shfl_xor(nss, 32);
  const float alpha = 1.f / (sqrtf(nss) + 1e-8f);

  float* eo = (dir ? envR : envL) + (size_t)b * 64;
#pragma unroll
  for (int mt = 0; mt < 4; mt++) {
    vf4 v;
#pragma unroll
    for (int r = 0; r < 4; r++) v[r] = u[mt][r] * alpha;
    *(vf4*)&eo[16 * mt + 4 * g] = v;
  }
}

// ---- center contraction (fp32) ----
__global__ __launch_bounds__(256) void centerk(const float* __restrict__ envL,
                                               const float* __restrict__ envR,
                                               const float* __restrict__ center,
                                               float* __restrict__ Pp) {
  __shared__ float Cs[2][SITE_F];
  __shared__ float LT[64 * 36];
  __shared__ float RT[64 * 36];
  const int bbase = blockIdx.x * 32;
  const int half = blockIdx.y;
  const int tid = threadIdx.x;
  const int och = tid & 31, bch = tid >> 5;
  const int o0 = och * 4, b0 = bch * 4;
#pragma unroll
  for (int m = 0; m < 8; m++) {
    const int idx = m * 256 + tid;
    const int b = idx >> 6, l = idx & 63;
    LT[l * 36 + b] = envL[(bbase + b) * 64 + l];
    RT[l * 36 + b] = envR[(bbase + b) * 64 + l];
  }
  stage32k_256(Cs[0], center + (half * 32) * SITE_F, tid);
  float acc[4][4] = {};
  for (int lh = 0; lh < 32; lh++) {
    __syncthreads();
    const int buf = lh & 1;
    if (lh + 1 < 32) stage32k_256(Cs[buf ^ 1], center + (half * 32 + lh + 1) * SITE_F, tid);
    const vf4 lv = *(const vf4*)&LT[(half * 32 + lh) * 36 + b0];
    const float* C = Cs[buf];
#pragma unroll
    for (int r = 0; r < 64; r++) {
      const vf4 rv = *(const vf4*)&RT[r * 36 + b0];
      const vf4 cv = *(const vf4*)&C[r * 128 + o0];
#pragma unroll
      for (int i2 = 0; i2 < 4; i2++) {
        const float w = lv[i2] * rv[i2];
        acc[i2][0] += w * cv[0];
        acc[i2][1] += w * cv[1];
        acc[i2][2] += w * cv[2];
        acc[i2][3] += w * cv[3];
      }
    }
  }
#pragma unroll
  for (int i2 = 0; i2 < 4; i2++) {
    vf4 v; v[0] = acc[i2][0]; v[1] = acc[i2][1]; v[2] = acc[i2][2]; v[3] = acc[i2][3];
    *(vf4*)&Pp[(size_t)half * BBATCH * 128 + (size_t)(bbase + b0 + i2) * 128 + o0] = v;
  }
}

// ---- combine halves + row-normalize ----
__global__ __launch_bounds__(256) void combinek(const float* __restrict__ P,
                                                float* __restrict__ out) {
  const float* P0 = P;
  const float* P1 = P + (size_t)BBATCH * 128;
  const int row = blockIdx.x * 8 + (threadIdx.x >> 5);
  const int o0 = (threadIdx.x & 31) * 4;
  vf4 v = *(const vf4*)&P0[(size_t)row * 128 + o0];
  const vf4 v1 = *(const vf4*)&P1[(size_t)row * 128 + o0];
  v += v1;
  float ss = v[0] * v[0] + v[1] * v[1] + v[2] * v[2] + v[3] * v[3];
#pragma unroll
  for (int m = 1; m < 32; m <<= 1) ss += __shfl_xor(ss, m);
  const float inv = 1.f / fmaxf(sqrtf(ss), 1e-12f);
  v *= inv;
  *(vf4*)&out[(size_t)row * 128 + o0] = v;
}

extern "C" void kernel_launch(void* const* d_in, const int* in_sizes, int n_in,
                              void* d_out, int out_size, void* d_ws, size_t ws_size,
                              hipStream_t stream) {
  const float* x = (const float*)d_in[0];
  const float* left0 = (const float*)d_in[1];
  const float* left_rest = (const float*)d_in[2];
  const float* center = (const float*)d_in[3];
  const float* right_rest = (const float*)d_in[4];
  const float* right_last = (const float*)d_in[5];
  float* out = (float*)d_out;

  char* wsb = (char*)d_ws;
  unsigned short* Wl = (unsigned short*)wsb;                       // 8.37 MB
  unsigned short* Wr = Wl + (size_t)NS * SITE_F;                   // 8.37 MB
  float* envL = (float*)(Wr + (size_t)NS * SITE_F);                // 1 MB
  float* envR = envL + (size_t)BBATCH * 64;                        // 1 MB
  float* Pp = envR + (size_t)BBATCH * 64;                          // 4.2 MB

  hipLaunchKernelGGL(prep, dim3(NS, 2), dim3(256), 0, stream,
                     left_rest, right_rest, Wl, Wr);
  hipLaunchKernelGGL(sweep, dim3(512), dim3(64), 0, stream,
                     x, left0, right_last, Wl, Wr, envL, envR);
  hipLaunchKernelGGL(centerk, dim3(BBATCH / 32, 2), dim3(256), 0, stream,
                     envL, envR, center, Pp);
  hipLaunchKernelGGL(combinek, dim3(BBATCH / 8), dim3(256), 0, stream, Pp, out);
}

// Round 14
// 387.582 us; speedup vs baseline: 1.5580x; 1.3114x over previous
//
#include <hip/hip_runtime.h>

typedef float vf4 __attribute__((ext_vector_type(4)));
typedef int vi4 __attribute__((ext_vector_type(4)));
typedef short short8 __attribute__((ext_vector_type(8)));
typedef unsigned short ushort8 __attribute__((ext_vector_type(8)));

#define LL 1024
#define DD 64
#define OO 128
#define BBATCH 4096
#define NS 511          // scan sites per sweep
#define SITE_F 8192     // elements per site tensor (64*2*64)

// ---- async global->LDS ----
__device__ __forceinline__ void gld_lds16(const float* g, float* l) {
  __builtin_amdgcn_global_load_lds(
      (const __attribute__((address_space(1))) unsigned int*)g,
      (__attribute__((address_space(3))) unsigned int*)l, 16, 0, 0);
}

__device__ __forceinline__ void stage32k_256(float* lds, const float* g, int tid) {
#pragma unroll
  for (int q = 0; q < 8; q++) {
    const int off = (q * 256 + tid) * 4;
    gld_lds16(g + off, lds + off);
  }
}

// ---- one-shot: build bf16 16x16x32-frag-major N = A - I for both sweeps ----
// layout: W[site][f][lane][j] bf16, f = mt*4+s (mt=M-tile 0..3, s=K-step 0..3)
// A elem: m = 16*mt + (lane&15); k = 32*s + 8*(lane>>4) + j  (k = 2*env_in + p)
// right buffer is site-reversed so the sweep always walks ascending.
// (verbatim from R7/R13 — numerics proven, absmax 2.441e-3)
__global__ __launch_bounds__(256) void prep(const float* __restrict__ lsrc,
                                            const float* __restrict__ rsrc,
                                            unsigned short* __restrict__ Wl,
                                            unsigned short* __restrict__ Wr) {
  __shared__ float S[SITE_F];
  const int site = blockIdx.x;
  const int dir = blockIdx.y;
  const int tid = threadIdx.x;
  const float* src = (dir ? rsrc : lsrc) + (size_t)site * SITE_F;
  unsigned short* dst = dir ? (Wr + (size_t)(NS - 1 - site) * SITE_F)
                            : (Wl + (size_t)site * SITE_F);
#pragma unroll
  for (int m = 0; m < 8; m++)
    *(vf4*)&S[(m * 256 + tid) * 4] = *(const vf4*)&src[(m * 256 + tid) * 4];
  __syncthreads();
#pragma unroll
  for (int q = 0; q < 4; q++) {
    const int slot = q * 256 + tid;           // 0..1023 = f*64 + lane
    const int lane = slot & 63, f = slot >> 6;
    const int mt = f >> 2, s = f & 3;
    const int g = lane >> 4, c = lane & 15;
    const int m = 16 * mt + c;
    ushort8 t;
#pragma unroll
    for (int j = 0; j < 8; j++) {
      const int k = 32 * s + 8 * g + j;
      float v;
      if (dir == 0) {
        const int l = k >> 1, p = k & 1;
        v = S[l * 128 + p * 64 + m] - ((m == l) ? 1.f : 0.f);
      } else {
        const int r = k >> 1, p = k & 1;
        v = S[m * 128 + p * 64 + r] - ((m == r) ? 1.f : 0.f);
      }
      const unsigned uu = __builtin_bit_cast(unsigned, v);
      t[j] = (unsigned short)((uu + 0x7FFFu + ((uu >> 16) & 1u)) >> 16);  // RNE
    }
    *(ushort8*)&dst[(size_t)slot * 8] = t;
  }
}

// ---- stage one 4-site group (64KB) with 128 threads (32 ops/thread) ----
#define STAGE_GROUP(G, BUF)                                                    \
  {                                                                            \
    _Pragma("unroll")                                                          \
    for (int s4 = 0; s4 < 4; s4++) {                                           \
      int st_ = (G) * 4 + s4;                                                  \
      if (st_ > NS - 1) st_ = NS - 1;                                          \
      const float* Ws_ = Wf + (size_t)st_ * 4096;                              \
      float* d_ = &ring[BUF][s4][0];                                           \
      _Pragma("unroll")                                                        \
      for (int q = 0; q < 8; q++)                                              \
        gld_lds16(Ws_ + q * 512 + tid * 4, d_ + q * 512 + tid * 4);            \
    }                                                                          \
  }

// ---- per-site body: W from resident LDS, pure compiler scheduling ----
// I: runtime site index. CS/SN: cos/sin(site I); updated to site I+1's.
#define BODY(I, BUF, S4)                                                       \
  {                                                                            \
    const float* rb = &ring[BUF][S4][0];                                       \
    vf4 FC[16];                                                                \
    _Pragma("unroll")                                                          \
    for (int q = 0; q < 16; q++)                                               \
      FC[q] = *(const vf4*)&rb[(q * 64 + lane) * 4];                           \
    const int nI = (I) + 1;                                                    \
    float xn = 0.f;                                                            \
    if (nI <= NS - 1) xn = xrow[dir ? (1022 - nI) : (1 + nI)];                 \
    short8 e2[4];                                                              \
    _Pragma("unroll")                                                          \
    for (int s = 0; s < 4; s++) {                                              \
      int pk[4];                                                               \
      _Pragma("unroll")                                                        \
      for (int t = 0; t < 4; t++) {                                            \
        const float f0 = u[s][t] * CS, f1 = u[s][t] * SN;                      \
        int p;                                                                 \
        asm("v_cvt_pk_bf16_f32 %0, %1, %2" : "=v"(p) : "v"(f0), "v"(f1));      \
        pk[t] = p;                                                             \
      }                                                                        \
      e2[s] = __builtin_bit_cast(short8, (vi4){pk[0], pk[1], pk[2], pk[3]});   \
    }                                                                          \
    const float keff = CS + SN;                                                \
    vf4 acc[4];                                                                \
    _Pragma("unroll")                                                          \
    for (int mt = 0; mt < 4; mt++) {                                           \
      vf4 z;                                                                   \
      z[0] = keff * u[mt][0]; z[1] = keff * u[mt][1];                          \
      z[2] = keff * u[mt][2]; z[3] = keff * u[mt][3];                          \
      acc[mt] = z;                                                             \
    }                                                                          \
    _Pragma("unroll")                                                          \
    for (int mt = 0; mt < 4; mt++) {                                           \
      acc[mt] = __builtin_amdgcn_mfma_f32_16x16x32_bf16(                       \
          __builtin_bit_cast(short8, FC[mt * 4 + 0]), e2[0], acc[mt], 0, 0, 0);\
      acc[mt] = __builtin_amdgcn_mfma_f32_16x16x32_bf16(                       \
          __builtin_bit_cast(short8, FC[mt * 4 + 1]), e2[1], acc[mt], 0, 0, 0);\
      acc[mt] = __builtin_amdgcn_mfma_f32_16x16x32_bf16(                       \
          __builtin_bit_cast(short8, FC[mt * 4 + 2]), e2[2], acc[mt], 0, 0, 0);\
      acc[mt] = __builtin_amdgcn_mfma_f32_16x16x32_bf16(                       \
          __builtin_bit_cast(short8, FC[mt * 4 + 3]), e2[3], acc[mt], 0, 0, 0);\
    }                                                                          \
    _Pragma("unroll")                                                          \
    for (int mt = 0; mt < 4; mt++) u[mt] = acc[mt];                            \
    if (nI <= NS - 1) { /* cs/sn(site I+1) */                                  \
      const float qrev = 0.25f * xn; /* cos(pi/2 x)=cos(2pi*(x/4)) */          \
      float c_, s_;                                                            \
      asm("v_cos_f32 %0, %1" : "=v"(c_) : "v"(qrev));                          \
      asm("v_sin_f32 %0, %1" : "=v"(s_) : "v"(qrev));                          \
      CS = c_;                                                                 \
      SN = s_;                                                                 \
    }                                                                          \
    if (((I) & 7) == 7) { /* exact pow2 rescale, keeps fp32 in range */        \
      float nss = 0.f;                                                         \
      _Pragma("unroll")                                                        \
      for (int mt = 0; mt < 4; mt++)                                           \
        _Pragma("unroll")                                                      \
        for (int r = 0; r < 4; r++) nss += u[mt][r] * u[mt][r];                \
      nss += __shfl_xor(nss, 16);                                              \
      nss += __shfl_xor(nss, 32);                                              \
      const int eb = (__float_as_int(nss) >> 23) & 0xFF;                       \
      const float alpha = __int_as_float((127 - ((eb - 127) >> 1)) << 23);     \
      _Pragma("unroll")                                                        \
      for (int mt = 0; mt < 4; mt++)                                           \
        _Pragma("unroll")                                                      \
        for (int r = 0; r < 4; r++) u[mt][r] *= alpha;                         \
    }                                                                          \
  }

// ---- sweep: 256 blocks x 2 waves; each wave = one 16-sample chain; the two
// waves share a 4-site 64KB W group, double-buffered, ONE barrier per group
// (m97 pattern: the vmcnt drain folds into s_barrier, amortized over 4 sites).
// XCD swizzle: XCDs 0-3 -> dir 0, XCDs 4-7 -> dir 1.
__global__ __launch_bounds__(128, 1) void sweep(const float* __restrict__ x,
                                                const float* __restrict__ left0,
                                                const float* __restrict__ right_last,
                                                const unsigned short* __restrict__ Wl,
                                                const unsigned short* __restrict__ Wr,
                                                float* __restrict__ envL,
                                                float* __restrict__ envR) {
  __shared__ float ring[2][4][4096];   // 2 groups x 4 sites x 16KB = 128KB
  const int bid = blockIdx.x;          // 0..255
  const int xcd = bid & 7;
  const int dir = xcd >> 2;
  const int slot = (xcd & 3) * 32 + (bid >> 3);   // 0..127 within dir
  const int tid = threadIdx.x;
  const int wave = tid >> 6;
  const int lane = tid & 63;
  const int g_ = lane >> 4, c = lane & 15;
  const int b = (slot * 2 + wave) * 16 + c;
  const float* xrow = x + (size_t)b * LL;

  const float* Wf = (const float*)(dir ? Wr : Wl);

  // init env from boundary tensor (fp32, exact normalize; compiler loads)
  vf4 u[4];
  {
    const float x0 = xrow[dir ? (LL - 1) : 0];
    const float qrev = 0.25f * x0;
    float cs, sn;
    asm("v_cos_f32 %0, %1" : "=v"(cs) : "v"(qrev));
    asm("v_sin_f32 %0, %1" : "=v"(sn) : "v"(qrev));
#pragma unroll
    for (int mt = 0; mt < 4; mt++)
#pragma unroll
      for (int r = 0; r < 4; r++) {
        const int n = 16 * mt + 4 * g_ + r;
        const float w0 = dir ? right_last[n * 2] : left0[n];
        const float w1 = dir ? right_last[n * 2 + 1] : left0[64 + n];
        u[mt][r] = cs * w0 + sn * w1;
      }
    float ss = 0.f;
#pragma unroll
    for (int mt = 0; mt < 4; mt++)
#pragma unroll
      for (int r = 0; r < 4; r++) ss += u[mt][r] * u[mt][r];
    ss += __shfl_xor(ss, 16);
    ss += __shfl_xor(ss, 32);
    const float a0 = 1.f / (sqrtf(ss) + 1e-8f);
#pragma unroll
    for (int mt = 0; mt < 4; mt++)
#pragma unroll
      for (int r = 0; r < 4; r++) u[mt][r] *= a0;
  }

  // cs/sn(site 0)
  float CS, SN;
  {
    const float q0 = 0.25f * xrow[dir ? 1022 : 1];
    asm("v_cos_f32 %0, %1" : "=v"(CS) : "v"(q0));
    asm("v_sin_f32 %0, %1" : "=v"(SN) : "v"(q0));
  }

  // ---- prologue: stage group 0, barrier (drains staging) ----
  STAGE_GROUP(0, 0)
  __syncthreads();

  // ---- main loop: 127 full groups (sites 0..507) ----
  for (int g = 0; g < 127; g++) {
    const int buf = g & 1;
    STAGE_GROUP(g + 1, buf ^ 1)     // prefetch next group while computing
    const int i0 = g * 4;
    BODY(i0 + 0, buf, 0)
    BODY(i0 + 1, buf, 1)
    BODY(i0 + 2, buf, 2)
    BODY(i0 + 3, buf, 3)
    __syncthreads();                // drain stage(g+1); buf reusable
  }
  // ---- tail group 127: sites 508..510 in buf 1 ----
  BODY(508, 1, 0)
  BODY(509, 1, 1)
  BODY(510, 1, 2)

  // final exact normalize + store
  float nss = 0.f;
#pragma unroll
  for (int mt = 0; mt < 4; mt++)
#pragma unroll
    for (int r = 0; r < 4; r++) nss += u[mt][r] * u[mt][r];
  nss += __shfl_xor(nss, 16);
  nss += __shfl_xor(nss, 32);
  const float alpha = 1.f / (sqrtf(nss) + 1e-8f);

  float* eo = (dir ? envR : envL) + (size_t)b * 64;
#pragma unroll
  for (int mt = 0; mt < 4; mt++) {
    vf4 v;
#pragma unroll
    for (int r = 0; r < 4; r++) v[r] = u[mt][r] * alpha;
    *(vf4*)&eo[16 * mt + 4 * g_] = v;
  }
}

// ---- center contraction (fp32) ----
__global__ __launch_bounds__(256) void centerk(const float* __restrict__ envL,
                                               const float* __restrict__ envR,
                                               const float* __restrict__ center,
                                               float* __restrict__ Pp) {
  __shared__ float Cs[2][SITE_F];
  __shared__ float LT[64 * 36];
  __shared__ float RT[64 * 36];
  const int bbase = blockIdx.x * 32;
  const int half = blockIdx.y;
  const int tid = threadIdx.x;
  const int och = tid & 31, bch = tid >> 5;
  const int o0 = och * 4, b0 = bch * 4;
#pragma unroll
  for (int m = 0; m < 8; m++) {
    const int idx = m * 256 + tid;
    const int b = idx >> 6, l = idx & 63;
    LT[l * 36 + b] = envL[(bbase + b) * 64 + l];
    RT[l * 36 + b] = envR[(bbase + b) * 64 + l];
  }
  stage32k_256(Cs[0], center + (half * 32) * SITE_F, tid);
  float acc[4][4] = {};
  for (int lh = 0; lh < 32; lh++) {
    __syncthreads();
    const int buf = lh & 1;
    if (lh + 1 < 32) stage32k_256(Cs[buf ^ 1], center + (half * 32 + lh + 1) * SITE_F, tid);
    const vf4 lv = *(const vf4*)&LT[(half * 32 + lh) * 36 + b0];
    const float* C = Cs[buf];
#pragma unroll
    for (int r = 0; r < 64; r++) {
      const vf4 rv = *(const vf4*)&RT[r * 36 + b0];
      const vf4 cv = *(const vf4*)&C[r * 128 + o0];
#pragma unroll
      for (int i2 = 0; i2 < 4; i2++) {
        const float w = lv[i2] * rv[i2];
        acc[i2][0] += w * cv[0];
        acc[i2][1] += w * cv[1];
        acc[i2][2] += w * cv[2];
        acc[i2][3] += w * cv[3];
      }
    }
  }
#pragma unroll
  for (int i2 = 0; i2 < 4; i2++) {
    vf4 v; v[0] = acc[i2][0]; v[1] = acc[i2][1]; v[2] = acc[i2][2]; v[3] = acc[i2][3];
    *(vf4*)&Pp[(size_t)half * BBATCH * 128 + (size_t)(bbase + b0 + i2) * 128 + o0] = v;
  }
}

// ---- combine halves + row-normalize ----
__global__ __launch_bounds__(256) void combinek(const float* __restrict__ P,
                                                float* __restrict__ out) {
  const float* P0 = P;
  const float* P1 = P + (size_t)BBATCH * 128;
  const int row = blockIdx.x * 8 + (threadIdx.x >> 5);
  const int o0 = (threadIdx.x & 31) * 4;
  vf4 v = *(const vf4*)&P0[(size_t)row * 128 + o0];
  const vf4 v1 = *(const vf4*)&P1[(size_t)row * 128 + o0];
  v += v1;
  float ss = v[0] * v[0] + v[1] * v[1] + v[2] * v[2] + v[3] * v[3];
#pragma unroll
  for (int m = 1; m < 32; m <<= 1) ss += __shfl_xor(ss, m);
  const float inv = 1.f / fmaxf(sqrtf(ss), 1e-12f);
  v *= inv;
  *(vf4*)&out[(size_t)row * 128 + o0] = v;
}

extern "C" void kernel_launch(void* const* d_in, const int* in_sizes, int n_in,
                              void* d_out, int out_size, void* d_ws, size_t ws_size,
                              hipStream_t stream) {
  const float* x = (const float*)d_in[0];
  const float* left0 = (const float*)d_in[1];
  const float* left_rest = (const float*)d_in[2];
  const float* center = (const float*)d_in[3];
  const float* right_rest = (const float*)d_in[4];
  const float* right_last = (const float*)d_in[5];
  float* out = (float*)d_out;

  char* wsb = (char*)d_ws;
  unsigned short* Wl = (unsigned short*)wsb;                       // 8.37 MB
  unsigned short* Wr = Wl + (size_t)NS * SITE_F;                   // 8.37 MB
  float* envL = (float*)(Wr + (size_t)NS * SITE_F);                // 1 MB
  float* envR = envL + (size_t)BBATCH * 64;                        // 1 MB
  float* Pp = envR + (size_t)BBATCH * 64;                          // 4.2 MB

  hipLaunchKernelGGL(prep, dim3(NS, 2), dim3(256), 0, stream,
                     left_rest, right_rest, Wl, Wr);
  hipLaunchKernelGGL(sweep, dim3(256), dim3(128), 0, stream,
                     x, left0, right_last, Wl, Wr, envL, envR);
  hipLaunchKernelGGL(centerk, dim3(BBATCH / 32, 2), dim3(256), 0, stream,
                     envL, envR, center, Pp);
  hipLaunchKernelGGL(combinek, dim3(BBATCH / 8), dim3(256), 0, stream, Pp, out);
}

// Round 15
// 320.208 us; speedup vs baseline: 1.8858x; 1.2104x over previous
//
#include <hip/hip_runtime.h>

typedef float vf4 __attribute__((ext_vector_type(4)));
typedef int vi4 __attribute__((ext_vector_type(4)));
typedef int vi2 __attribute__((ext_vector_type(2)));
typedef short short8 __attribute__((ext_vector_type(8)));
typedef unsigned short ushort8 __attribute__((ext_vector_type(8)));

#define LL 1024
#define DD 64
#define OO 128
#define BBATCH 4096
#define NS 511          // scan sites per sweep
#define SITE_F 8192     // elements per site tensor (64*2*64)

// ---- async global->LDS ----
__device__ __forceinline__ void gld_lds16(const float* g, float* l) {
  __builtin_amdgcn_global_load_lds(
      (const __attribute__((address_space(1))) unsigned int*)g,
      (__attribute__((address_space(3))) unsigned int*)l, 16, 0, 0);
}

__device__ __forceinline__ unsigned short f2bf(float v) {
  const unsigned uu = __builtin_bit_cast(unsigned, v);
  return (unsigned short)((uu + 0x7FFFu + ((uu >> 16) & 1u)) >> 16);  // RNE
}

// ---- one-shot: build bf16 16x16x32-frag-major N = A - I for both sweeps ----
// (verbatim from R7/R13 — numerics proven, absmax 2.441e-3)
__global__ __launch_bounds__(256) void prep(const float* __restrict__ lsrc,
                                            const float* __restrict__ rsrc,
                                            unsigned short* __restrict__ Wl,
                                            unsigned short* __restrict__ Wr) {
  __shared__ float S[SITE_F];
  const int site = blockIdx.x;
  const int dir = blockIdx.y;
  const int tid = threadIdx.x;
  const float* src = (dir ? rsrc : lsrc) + (size_t)site * SITE_F;
  unsigned short* dst = dir ? (Wr + (size_t)(NS - 1 - site) * SITE_F)
                            : (Wl + (size_t)site * SITE_F);
#pragma unroll
  for (int m = 0; m < 8; m++)
    *(vf4*)&S[(m * 256 + tid) * 4] = *(const vf4*)&src[(m * 256 + tid) * 4];
  __syncthreads();
#pragma unroll
  for (int q = 0; q < 4; q++) {
    const int slot = q * 256 + tid;           // 0..1023 = f*64 + lane
    const int lane = slot & 63, f = slot >> 6;
    const int mt = f >> 2, s = f & 3;
    const int g = lane >> 4, c = lane & 15;
    const int m = 16 * mt + c;
    ushort8 t;
#pragma unroll
    for (int j = 0; j < 8; j++) {
      const int k = 32 * s + 8 * g + j;
      float v;
      if (dir == 0) {
        const int l = k >> 1, p = k & 1;
        v = S[l * 128 + p * 64 + m] - ((m == l) ? 1.f : 0.f);
      } else {
        const int r = k >> 1, p = k & 1;
        v = S[m * 128 + p * 64 + r] - ((m == r) ? 1.f : 0.f);
      }
      t[j] = f2bf(v);
    }
    *(ushort8*)&dst[(size_t)slot * 8] = t;
  }
}

// ---- one-shot: pack center C[l][r][o] into per-o A-frags (bf16) ----
// Cf[o][f][lane][j], f = mt*2+s; elem = C[l][r][o], l = 16mt + (lane&15),
// r = 32s + 8*(lane>>4) + j   (same A-layout as prep)
__global__ __launch_bounds__(256) void prep2(const float* __restrict__ center,
                                             unsigned short* __restrict__ Cf) {
  __shared__ float S[4096];        // C[:,:,o] slab, [l*64+r]
  const int o = blockIdx.x;
  const int tid = threadIdx.x;
#pragma unroll
  for (int k = 0; k < 16; k++) {
    const int idx = k * 256 + tid;
    S[idx] = center[(size_t)idx * 128 + o];
  }
  __syncthreads();
#pragma unroll
  for (int q = 0; q < 2; q++) {
    const int slot = q * 256 + tid;           // 0..511 = f*64 + lane
    const int lane = slot & 63, f = slot >> 6;
    const int mt = f >> 1, s = f & 1;
    const int g = lane >> 4, c = lane & 15;
    const int l = 16 * mt + c;
    ushort8 t;
#pragma unroll
    for (int j = 0; j < 8; j++) {
      const int r = 32 * s + 8 * g + j;
      t[j] = f2bf(S[l * 64 + r]);
    }
    *(ushort8*)&Cf[(size_t)((o * 8 + f) * 64 + lane) * 8] = t;
  }
}

// ---- stage one 4-site group (64KB) with 128 threads ----
#define STAGE_GROUP(G, BUF)                                                    \
  {                                                                            \
    _Pragma("unroll")                                                          \
    for (int s4 = 0; s4 < 4; s4++) {                                           \
      int st_ = (G) * 4 + s4;                                                  \
      if (st_ > NS - 1) st_ = NS - 1;                                          \
      const float* Ws_ = Wf + (size_t)st_ * 4096;                              \
      float* d_ = &ring[BUF][s4][0];                                           \
      _Pragma("unroll")                                                        \
      for (int q = 0; q < 8; q++)                                              \
        gld_lds16(Ws_ + q * 512 + tid * 4, d_ + q * 512 + tid * 4);            \
    }                                                                          \
  }

#define LOAD_FC(FC, RB)                                                        \
  {                                                                            \
    const float* rb_ = (RB);                                                   \
    _Pragma("unroll")                                                          \
    for (int q = 0; q < 16; q++)                                               \
      FC[q] = *(const vf4*)&rb_[(q * 64 + lane) * 4];                          \
  }

// ---- per-site body: compute with FCc; prefetch FCn <- RBN when PF ----
#define BODYP(I, FCc, FCn, RBN, PF)                                            \
  {                                                                            \
    if (PF) {                                                                  \
      LOAD_FC(FCn, RBN)                                                        \
      __builtin_amdgcn_sched_barrier(0);                                       \
    }                                                                          \
    const int nI = (I) + 1;                                                    \
    float xn = 0.f;                                                            \
    if (nI <= NS - 1) xn = xrow[dir ? (1022 - nI) : (1 + nI)];                 \
    short8 e2[4];                                                              \
    _Pragma("unroll")                                                          \
    for (int s = 0; s < 4; s++) {                                              \
      int pk[4];                                                               \
      _Pragma("unroll")                                                        \
      for (int t = 0; t < 4; t++) {                                            \
        const float f0 = u[s][t] * CS, f1 = u[s][t] * SN;                      \
        int p;                                                                 \
        asm("v_cvt_pk_bf16_f32 %0, %1, %2" : "=v"(p) : "v"(f0), "v"(f1));      \
        pk[t] = p;                                                             \
      }                                                                        \
      e2[s] = __builtin_bit_cast(short8, (vi4){pk[0], pk[1], pk[2], pk[3]});   \
    }                                                                          \
    const float keff = CS + SN;                                                \
    vf4 accA[4], accB[4];                                                      \
    _Pragma("unroll")                                                          \
    for (int mt = 0; mt < 4; mt++) {                                           \
      vf4 z;                                                                   \
      z[0] = keff * u[mt][0]; z[1] = keff * u[mt][1];                          \
      z[2] = keff * u[mt][2]; z[3] = keff * u[mt][3];                          \
      accA[mt] = z;                                                            \
      accB[mt] = (vf4){0.f, 0.f, 0.f, 0.f};                                    \
    }                                                                          \
    _Pragma("unroll")                                                          \
    for (int mt = 0; mt < 4; mt++) {                                           \
      accA[mt] = __builtin_amdgcn_mfma_f32_16x16x32_bf16(                      \
          __builtin_bit_cast(short8, FCc[mt * 4 + 0]), e2[0], accA[mt], 0,0,0);\
      accA[mt] = __builtin_amdgcn_mfma_f32_16x16x32_bf16(                      \
          __builtin_bit_cast(short8, FCc[mt * 4 + 1]), e2[1], accA[mt], 0,0,0);\
      accB[mt] = __builtin_amdgcn_mfma_f32_16x16x32_bf16(                      \
          __builtin_bit_cast(short8, FCc[mt * 4 + 2]), e2[2], accB[mt], 0,0,0);\
      accB[mt] = __builtin_amdgcn_mfma_f32_16x16x32_bf16(                      \
          __builtin_bit_cast(short8, FCc[mt * 4 + 3]), e2[3], accB[mt], 0,0,0);\
    }                                                                          \
    _Pragma("unroll")                                                          \
    for (int mt = 0; mt < 4; mt++) u[mt] = accA[mt] + accB[mt];                \
    if (nI <= NS - 1) {                                                        \
      const float qrev = 0.25f * xn; /* cos(pi/2 x)=cos(2pi*(x/4)) */          \
      float c_, s_;                                                            \
      asm("v_cos_f32 %0, %1" : "=v"(c_) : "v"(qrev));                          \
      asm("v_sin_f32 %0, %1" : "=v"(s_) : "v"(qrev));                          \
      CS = c_;                                                                 \
      SN = s_;                                                                 \
    }                                                                          \
    if (((I) & 7) == 7) { /* exact pow2 rescale */                             \
      float nss = 0.f;                                                         \
      _Pragma("unroll")                                                        \
      for (int mt = 0; mt < 4; mt++)                                           \
        _Pragma("unroll")                                                      \
        for (int r = 0; r < 4; r++) nss += u[mt][r] * u[mt][r];                \
      nss += __shfl_xor(nss, 16);                                              \
      nss += __shfl_xor(nss, 32);                                              \
      const int eb = (__float_as_int(nss) >> 23) & 0xFF;                       \
      const float alpha = __int_as_float((127 - ((eb - 127) >> 1)) << 23);     \
      _Pragma("unroll")                                                        \
      for (int mt = 0; mt < 4; mt++)                                           \
        _Pragma("unroll")                                                      \
        for (int r = 0; r < 4; r++) u[mt][r] *= alpha;                         \
    }                                                                          \
  }

// ---- sweep: 256 blocks x 2 waves (16-sample chains); group dbuf + FC dbuf --
__global__ __launch_bounds__(128, 1) void sweep(const float* __restrict__ x,
                                                const float* __restrict__ left0,
                                                const float* __restrict__ right_last,
                                                const unsigned short* __restrict__ Wl,
                                                const unsigned short* __restrict__ Wr,
                                                float* __restrict__ envL,
                                                float* __restrict__ envR,
                                                unsigned short* __restrict__ Lb16,
                                                unsigned short* __restrict__ Rb16) {
  __shared__ float ring[2][4][4096];   // 2 groups x 4 sites x 16KB = 128KB
  const int bid = blockIdx.x;          // 0..255
  const int xcd = bid & 7;
  const int dir = xcd >> 2;
  const int slot = (xcd & 3) * 32 + (bid >> 3);   // 0..127 within dir
  const int tid = threadIdx.x;
  const int wave = tid >> 6;
  const int lane = tid & 63;
  const int g_ = lane >> 4, c = lane & 15;
  const int b = (slot * 2 + wave) * 16 + c;
  const float* xrow = x + (size_t)b * LL;

  const float* Wf = (const float*)(dir ? Wr : Wl);

  // init env (fp32, exact normalize)
  vf4 u[4];
  {
    const float x0 = xrow[dir ? (LL - 1) : 0];
    const float qrev = 0.25f * x0;
    float cs, sn;
    asm("v_cos_f32 %0, %1" : "=v"(cs) : "v"(qrev));
    asm("v_sin_f32 %0, %1" : "=v"(sn) : "v"(qrev));
#pragma unroll
    for (int mt = 0; mt < 4; mt++)
#pragma unroll
      for (int r = 0; r < 4; r++) {
        const int n = 16 * mt + 4 * g_ + r;
        const float w0 = dir ? right_last[n * 2] : left0[n];
        const float w1 = dir ? right_last[n * 2 + 1] : left0[64 + n];
        u[mt][r] = cs * w0 + sn * w1;
      }
    float ss = 0.f;
#pragma unroll
    for (int mt = 0; mt < 4; mt++)
#pragma unroll
      for (int r = 0; r < 4; r++) ss += u[mt][r] * u[mt][r];
    ss += __shfl_xor(ss, 16);
    ss += __shfl_xor(ss, 32);
    const float a0 = 1.f / (sqrtf(ss) + 1e-8f);
#pragma unroll
    for (int mt = 0; mt < 4; mt++)
#pragma unroll
      for (int r = 0; r < 4; r++) u[mt][r] *= a0;
  }

  float CS, SN;
  {
    const float q0 = 0.25f * xrow[dir ? 1022 : 1];
    asm("v_cos_f32 %0, %1" : "=v"(CS) : "v"(q0));
    asm("v_sin_f32 %0, %1" : "=v"(SN) : "v"(q0));
  }

  STAGE_GROUP(0, 0)
  __syncthreads();

  vf4 fX[16], fY[16];
  for (int g = 0; g < 127; g++) {
    const int buf = g & 1;
    LOAD_FC(fX, &ring[buf][0][0])
    STAGE_GROUP(g + 1, buf ^ 1)     // prefetch next group while computing
    const int i0 = g * 4;
    BODYP(i0 + 0, fX, fY, &ring[buf][1][0], 1)
    BODYP(i0 + 1, fY, fX, &ring[buf][2][0], 1)
    BODYP(i0 + 2, fX, fY, &ring[buf][3][0], 1)
    BODYP(i0 + 3, fY, fX, &ring[buf][0][0], 0)
    __syncthreads();                // drain stage(g+1); buf reusable
  }
  // tail group 127: sites 508..510 in buf 1
  LOAD_FC(fX, &ring[1][0][0])
  BODYP(508, fX, fY, &ring[1][1][0], 1)
  BODYP(509, fY, fX, &ring[1][2][0], 1)
  BODYP(510, fX, fY, &ring[1][3][0], 0)

  // final exact normalize + store (f32 + bf16 fragment-ready copy)
  float nss = 0.f;
#pragma unroll
  for (int mt = 0; mt < 4; mt++)
#pragma unroll
    for (int r = 0; r < 4; r++) nss += u[mt][r] * u[mt][r];
  nss += __shfl_xor(nss, 16);
  nss += __shfl_xor(nss, 32);
  const float alpha = 1.f / (sqrtf(nss) + 1e-8f);

  float* eo = (dir ? envR : envL) + (size_t)b * 64;
  unsigned short* eo16 = (dir ? Rb16 : Lb16) + (size_t)b * 64;
#pragma unroll
  for (int mt = 0; mt < 4; mt++) {
    vf4 v;
#pragma unroll
    for (int r = 0; r < 4; r++) v[r] = u[mt][r] * alpha;
    *(vf4*)&eo[16 * mt + 4 * g_] = v;
    int p01, p23;
    asm("v_cvt_pk_bf16_f32 %0, %1, %2" : "=v"(p01) : "v"(v[0]), "v"(v[1]));
    asm("v_cvt_pk_bf16_f32 %0, %1, %2" : "=v"(p23) : "v"(v[2]), "v"(v[3]));
    *(vi2*)&eo16[16 * mt + 4 * g_] = (vi2){p01, p23};
  }
}

// ---- center contraction via MFMA: out[b,o] = L[b,:]·(C_o·R[b,:]^T) ----
// 256 blocks (16 b each) x 4 waves (32 o each) = 4 waves/CU.
__global__ __launch_bounds__(256) void centerk2(const float* __restrict__ envL,
                                                const unsigned short* __restrict__ Rb16,
                                                const unsigned short* __restrict__ Cf,
                                                float* __restrict__ Pp) {
  const int b0 = blockIdx.x * 16;
  const int tid = threadIdx.x;
  const int wave = tid >> 6;
  const int lane = tid & 63;
  const int g = lane >> 4, c = lane & 15;

  // B-frags: R[b0+c][r], r = 32s + 8g + j  (2 frags, loaded once)
  short8 rf[2];
#pragma unroll
  for (int s = 0; s < 2; s++)
    rf[s] = __builtin_bit_cast(short8,
        *(const ushort8*)&Rb16[(size_t)(b0 + c) * 64 + 32 * s + 8 * g]);

  // L values: L[b0+c][16mt + 4g + r] (4 vf4, loaded once)
  vf4 Lv[4];
#pragma unroll
  for (int mt = 0; mt < 4; mt++)
    Lv[mt] = *(const vf4*)&envL[(size_t)(b0 + c) * 64 + 16 * mt + 4 * g];

  for (int oi = 0; oi < 32; oi++) {
    const int o = wave * 32 + oi;
    const unsigned short* cb = Cf + (size_t)(o * 8) * 64 * 8;
    vf4 acc[4];
#pragma unroll
    for (int mt = 0; mt < 4; mt++) {
      const short8 a0 = __builtin_bit_cast(short8,
          *(const ushort8*)&cb[(size_t)((mt * 2 + 0) * 64 + lane) * 8]);
      const short8 a1 = __builtin_bit_cast(short8,
          *(const ushort8*)&cb[(size_t)((mt * 2 + 1) * 64 + lane) * 8]);
      vf4 z = {0.f, 0.f, 0.f, 0.f};
      z = __builtin_amdgcn_mfma_f32_16x16x32_bf16(a0, rf[0], z, 0, 0, 0);
      z = __builtin_amdgcn_mfma_f32_16x16x32_bf16(a1, rf[1], z, 0, 0, 0);
      acc[mt] = z;
    }
    // step 2: contract l with L (per-lane 16 terms, then g-group reduce)
    float ps = 0.f;
#pragma unroll
    for (int mt = 0; mt < 4; mt++)
#pragma unroll
      for (int r = 0; r < 4; r++) ps += Lv[mt][r] * acc[mt][r];
    ps += __shfl_xor(ps, 16);
    ps += __shfl_xor(ps, 32);
    if (g == 0) Pp[(size_t)(b0 + c) * 128 + o] = ps;
  }
}

// ---- row-normalize Pp -> out ----
__global__ __launch_bounds__(256) void combinek2(const float* __restrict__ P,
                                                 float* __restrict__ out) {
  const int row = blockIdx.x * 8 + (threadIdx.x >> 5);
  const int o0 = (threadIdx.x & 31) * 4;
  vf4 v = *(const vf4*)&P[(size_t)row * 128 + o0];
  float ss = v[0] * v[0] + v[1] * v[1] + v[2] * v[2] + v[3] * v[3];
#pragma unroll
  for (int m = 1; m < 32; m <<= 1) ss += __shfl_xor(ss, m);
  const float inv = 1.f / fmaxf(sqrtf(ss), 1e-12f);
  v *= inv;
  *(vf4*)&out[(size_t)row * 128 + o0] = v;
}

extern "C" void kernel_launch(void* const* d_in, const int* in_sizes, int n_in,
                              void* d_out, int out_size, void* d_ws, size_t ws_size,
                              hipStream_t stream) {
  const float* x = (const float*)d_in[0];
  const float* left0 = (const float*)d_in[1];
  const float* left_rest = (const float*)d_in[2];
  const float* center = (const float*)d_in[3];
  const float* right_rest = (const float*)d_in[4];
  const float* right_last = (const float*)d_in[5];
  float* out = (float*)d_out;

  char* wsb = (char*)d_ws;
  unsigned short* Wl = (unsigned short*)wsb;                         // 8.37 MB
  unsigned short* Wr = Wl + (size_t)NS * SITE_F;                     // 8.37 MB
  float* envL = (float*)(Wr + (size_t)NS * SITE_F);                  // 1 MB
  float* envR = envL + (size_t)BBATCH * 64;                          // 1 MB
  unsigned short* Lb16 = (unsigned short*)(envR + (size_t)BBATCH * 64);  // 0.5 MB
  unsigned short* Rb16 = Lb16 + (size_t)BBATCH * 64;                 // 0.5 MB
  unsigned short* Cf = Rb16 + (size_t)BBATCH * 64;                   // 1 MB
  float* Pp = (float*)(Cf + (size_t)OO * 8 * 64 * 8);                // 2 MB

  hipLaunchKernelGGL(prep, dim3(NS, 2), dim3(256), 0, stream,
                     left_rest, right_rest, Wl, Wr);
  hipLaunchKernelGGL(prep2, dim3(OO), dim3(256), 0, stream, center, Cf);
  hipLaunchKernelGGL(sweep, dim3(256), dim3(128), 0, stream,
                     x, left0, right_last, Wl, Wr, envL, envR, Lb16, Rb16);
  hipLaunchKernelGGL(centerk2, dim3(BBATCH / 16), dim3(256), 0, stream,
                     envL, Rb16, Cf, Pp);
  hipLaunchKernelGGL(combinek2, dim3(BBATCH / 8), dim3(256), 0, stream, Pp, out);
}